// Round 5
// baseline (902.079 us; speedup 1.0000x reference)
//
#include <hip/hip_runtime.h>

// SimpleMemoryNetwork: T=64,B=128,H=256,NI=2,NO=10, lambda=.95, eta=.5, sample=32, decision=8
// R5: BATCH-SLICED blocks — 64 blocks x (2 batches x full H=256), 512 threads.
//  * a/r recurrence, dot coeffs c_s=<r_t,o_s>, r/o history, rank-33 apply, y: all block-LOCAL.
//  * Weights streamed from (per-XCD, read-only) L2 each step, dwordx4 coalesced.
//  * o is DEAD for t in (32,56) (eta=0, not in decision window) -> skipped entirely.
//  * Only cross-block datum: mu (batch mean), flat 64-way all-reduce, NaN-sentinel
//    value-flagged u64 pairs, 4 rotating slots; polled one step late (hidden under
//    the next step's weight streaming). Slot safety: publish(m) => all blocks read
//    m-1 => (induction) slot of m-2 fully consumed before re-sentinel.

typedef unsigned long long u64;

#define HH 256
#define NSTEPS 64
#define SENT 0x7FC00000u
#define SENT_PAIR 0x7FC000007FC00000ull
#define AGENT __HIP_MEMORY_SCOPE_AGENT
#define RLX __ATOMIC_RELAXED

__device__ __forceinline__ u64 ld64(const u64* p){ return __hip_atomic_load(p,RLX,AGENT); }
__device__ __forceinline__ void st64s(u64* p,u64 v){ __hip_atomic_store(p,v,RLX,AGENT); }
__device__ __forceinline__ u64 pack2(float lo,float hi){
  return (u64)__float_as_uint(lo) | ((u64)__float_as_uint(hi)<<32);
}

__global__ __launch_bounds__(256) void smn_init(float* __restrict__ ws){
  unsigned i = blockIdx.x*256u + threadIdx.x;
  u64* mu = (u64*)ws;                       // mu64[4][64][128]
  for (unsigned k=i; k<32768u; k+=gridDim.x*256u) st64s(&mu[k], SENT_PAIR);
}

__global__ __launch_bounds__(512) void smn_main(
    const float* __restrict__ x_in, const float* __restrict__ W_sr,
    const float* __restrict__ W_ma, const float* __restrict__ W_ro,
    const float* __restrict__ W_ao, const float* __restrict__ W_ar,
    const float* __restrict__ W_ra, const float* __restrict__ W_a,
    const float* __restrict__ W_y,  const float* __restrict__ gvec,
    const float* __restrict__ bvec, float* __restrict__ out,
    float* __restrict__ ws)
{
  __shared__ __align__(16) float r_hist[33][2][HH];   // 67.6 KB
  __shared__ __align__(16) float o_hist[33][2][HH];   // 67.6 KB
  __shared__ __align__(16) float P[8][2][HH];         // 16 KB (k-split partials; aliased as mu gather buf)
  __shared__ __align__(16) float a_st[2][2][HH];      // state double buffer
  __shared__ __align__(16) float r_st[2][2][HH];
  __shared__ __align__(16) float opre[2][HH];         // o_pre, then o (in place)
  __shared__ float c_l[33][2];
  __shared__ float mu_l[HH];
  __shared__ float lam_pow[64];
  __shared__ float x_l[2][5];

  const int tid = threadIdx.x;
  const int bid = blockIdx.x;               // 64 blocks, batches 2*bid, 2*bid+1
  const int q = tid & 63, ks = tid >> 6;    // streaming map: col-quad q, k-slice ks
  const int cb = tid >> 8, cc = tid & 255;  // combine map: batch cb, column cc
  u64* mu64 = (u64*)ws;                     // [slot:4][blk:64][pair:128]

  // per-thread resident small weights (column cc)
  const float wma0=W_ma[cc], wma1=W_ma[HH+cc], wma2=W_ma[2*HH+cc];
  const float wsr0=W_sr[cc], wsr1=W_sr[HH+cc];
  const float g_r=gvec[cc], b_r=bvec[cc];
  if (tid<64) lam_pow[tid]=powf(0.95f,(float)tid);
  if (tid<10) x_l[tid/5][tid%5] = x_in[(bid*2 + tid/5)*5 + tid%5];   // x(0)
  __syncthreads();

  for (int t=0; t<=NSTEPS; ++t) {
    const int cu = t&1, pv = cu^1;
    // ================= state(t): a/r matvecs (block-local) =================
    if (t < NSTEPS) {
      if (t==0) {
        float va = fmaxf(x_l[cb][2]*wma0 + x_l[cb][3]*wma1 + x_l[cb][4]*wma2, 0.f);
        float vr = fmaxf(x_l[cb][0]*wsr0 + x_l[cb][1]*wsr1, 0.f);
        a_st[0][cb][cc]=va; r_st[0][cb][cc]=vr; r_hist[0][cb][cc]=vr;
        __syncthreads();
      } else {
        float aA[2][4]={}, aN[2][4]={};
        for (int kc=0;kc<8;++kc) {
          const int k4 = ks*32 + kc*4;
          const float4 a0=*(const float4*)&a_st[pv][0][k4];
          const float4 a1=*(const float4*)&a_st[pv][1][k4];
          const float4 r0=*(const float4*)&r_st[pv][0][k4];
          const float4 r1=*(const float4*)&r_st[pv][1][k4];
          #pragma unroll
          for (int kk=0;kk<4;++kk){
            const int k = k4+kk;
            const float4 wa=*(const float4*)&W_a [k*HH+q*4];
            const float4 wr=*(const float4*)&W_ra[k*HH+q*4];
            const float4 wn=*(const float4*)&W_ar[k*HH+q*4];
            const float av0=(&a0.x)[kk], av1=(&a1.x)[kk];
            const float rv0=(&r0.x)[kk], rv1=(&r1.x)[kk];
            #pragma unroll
            for (int j=0;j<4;++j){
              const float waj=(&wa.x)[j], wrj=(&wr.x)[j], wnj=(&wn.x)[j];
              aA[0][j] += av0*waj + rv0*wrj;
              aA[1][j] += av1*waj + rv1*wrj;
              aN[0][j] += av0*wnj;
              aN[1][j] += av1*wnj;
            }
          }
        }
        *(float4*)&P[ks][0][q*4] = make_float4(aA[0][0],aA[0][1],aA[0][2],aA[0][3]);
        *(float4*)&P[ks][1][q*4] = make_float4(aA[1][0],aA[1][1],aA[1][2],aA[1][3]);
        __syncthreads();
        { float s=0.f;
          #pragma unroll
          for (int e=0;e<8;++e) s += P[e][cb][cc];
          a_st[cu][cb][cc] = fmaxf(s + x_l[cb][2]*wma0 + x_l[cb][3]*wma1 + x_l[cb][4]*wma2, 0.f);
        }
        __syncthreads();
        *(float4*)&P[ks][0][q*4] = make_float4(aN[0][0],aN[0][1],aN[0][2],aN[0][3]);
        *(float4*)&P[ks][1][q*4] = make_float4(aN[1][0],aN[1][1],aN[1][2],aN[1][3]);
        __syncthreads();
        { float s=0.f;
          #pragma unroll
          for (int e=0;e<8;++e) s += P[e][cb][cc];
          float v = fmaxf(s + x_l[cb][0]*wsr0 + x_l[cb][1]*wsr1, 0.f);
          r_st[cu][cb][cc]=v;
          if (t<=32) r_hist[t][cb][cc]=v;
        }
        __syncthreads();
      }
      // prefetch x(t+1) (readers of x(t) are done; next read is 2+ barriers away)
      if (t+1 < NSTEPS && tid<10)
        x_l[tid/5][tid%5] = x_in[((t+1)*128 + bid*2 + tid/5)*5 + tid%5];
    }
    // ================= finish o(t-1): poll mu (published last step, now ready) =====
    if (t>=1) {
      const int tp = t-1;
      if (tp<=32 || tp>=56) {
        const int m = (tp<=32)? tp : tp-23;
        const u64 slotbase = (u64)(m&3)*8192;
        { const int j = tid & 127, g = tid >> 7;
          u64 vv[16]; unsigned om=0;
          const u64* bp = mu64 + slotbase + (u64)g*16*128 + j;
          while (om != 0xFFFFu) {
            #pragma unroll
            for (int i=0;i<16;++i) if (!(om&(1u<<i))) {
              u64 v = ld64(bp + i*128);
              if ((unsigned)v!=SENT && (unsigned)(v>>32)!=SENT){ vv[i]=v; om|=1u<<i; }
            }
            if (om != 0xFFFFu) __builtin_amdgcn_s_sleep(2);
          }
          float s0=0.f,s1=0.f;
          #pragma unroll
          for (int i=0;i<16;++i){ s0+=__uint_as_float((unsigned)vv[i]);
                                  s1+=__uint_as_float((unsigned)(vv[i]>>32)); }
          float* Pf=&P[0][0][0];
          Pf[(j*4+g)*2]=s0; Pf[(j*4+g)*2+1]=s1;
        }
        __syncthreads();
        if (tid<128){
          const float* Pf=&P[0][0][0];
          float m0=0.f,m1=0.f;
          #pragma unroll
          for (int g2=0;g2<4;++g2){ m0+=Pf[(tid*4+g2)*2]; m1+=Pf[(tid*4+g2)*2+1]; }
          mu_l[2*tid]=m0*(1.0f/128.0f); mu_l[2*tid+1]=m1*(1.0f/128.0f);
        }
        __syncthreads();
        { float o = fmaxf(g_r*(opre[cb][cc]-mu_l[cc])+b_r, 0.f);
          opre[cb][cc]=o;                       // opre now holds o(t-1)
          if (tp<=32) o_hist[tp][cb][cc]=o;
        }
        __syncthreads();
        if (tp>=56 && tid<320){                 // y(t-1) into decision window
          const int ow=tid>>4, l16=tid&15, b=ow/10, n=ow%10;
          float acc=0.f;
          #pragma unroll
          for (int i=0;i<16;++i){ int k=l16*16+i; acc+=opre[b][k]*W_y[k*10+n]; }
          acc+=__shfl_xor(acc,1); acc+=__shfl_xor(acc,2);
          acc+=__shfl_xor(acc,4); acc+=__shfl_xor(acc,8);
          if (l16==0) out[(tp-56)*1280 + (bid*2+b)*10 + n]=acc;
        }
      }
    }
    if (t==NSTEPS) break;
    // ================= o_pre(t) + mu publish (only when o is live) ============
    const bool osp = (t<=32 || t>=56);
    if (osp) {
      const int smax = (t-1<32)? (t-1) : 32;    // dot slots s=0..smax
      if (smax>=0) {
        const int pr=tid>>3, l8=tid&7;
        for (int pp=pr; pp<(smax+1)*2; pp+=64) {
          const int s=pp>>1, b=pp&1;
          float acc=0.f;
          const int cbase=l8*32;
          #pragma unroll 8
          for (int i2=0;i2<32;++i2) acc += r_st[cu][b][cbase+i2]*o_hist[s][b][cbase+i2];
          acc+=__shfl_xor(acc,1); acc+=__shfl_xor(acc,2); acc+=__shfl_xor(acc,4);
          if (l8==0) c_l[s][b]=acc;
        }
      }
      float aO[2][4]={};
      for (int kc=0;kc<8;++kc){
        const int k4=ks*32+kc*4;
        const float4 a0=*(const float4*)&a_st[cu][0][k4];
        const float4 a1=*(const float4*)&a_st[cu][1][k4];
        const float4 r0=*(const float4*)&r_st[cu][0][k4];
        const float4 r1=*(const float4*)&r_st[cu][1][k4];
        #pragma unroll
        for (int kk=0;kk<4;++kk){
          const int k=k4+kk;
          const float4 wo=*(const float4*)&W_ro[k*HH+q*4];
          const float4 wq=*(const float4*)&W_ao[k*HH+q*4];
          const float av0=(&a0.x)[kk], av1=(&a1.x)[kk];
          const float rv0=(&r0.x)[kk], rv1=(&r1.x)[kk];
          #pragma unroll
          for (int j=0;j<4;++j){
            const float woj=(&wo.x)[j], wqj=(&wq.x)[j];
            aO[0][j] += rv0*woj + av0*wqj;
            aO[1][j] += rv1*woj + av1*wqj;
          }
        }
      }
      *(float4*)&P[ks][0][q*4] = make_float4(aO[0][0],aO[0][1],aO[0][2],aO[0][3]);
      *(float4*)&P[ks][1][q*4] = make_float4(aO[1][0],aO[1][1],aO[1][2],aO[1][3]);
      __syncthreads();
      { float s=0.f;
        #pragma unroll
        for (int e=0;e<8;++e) s += P[e][cb][cc];
        for (int s2=0;s2<=smax;++s2)
          s += lam_pow[t-1-s2]*0.5f*c_l[s2][cb]*r_hist[s2][cb][cc];
        opre[cb][cc]=s;
      }
      __syncthreads();
      const int m=(t<=32)? t : t-23;
      if (tid<128){
        // re-sentinel my words of slot (m+2)%4 (occupant m-2: fully consumed — see header)
        st64s(mu64 + (u64)((m+2)&3)*8192 + bid*128 + tid, SENT_PAIR);
        float plo=opre[0][2*tid]+opre[1][2*tid];
        float phi=opre[0][2*tid+1]+opre[1][2*tid+1];
        st64s(mu64 + (u64)(m&3)*8192 + bid*128 + tid, pack2(plo,phi));
      }
    }
  }
}

extern "C" void kernel_launch(void* const* d_in, const int* in_sizes, int n_in,
                              void* d_out, int out_size, void* d_ws, size_t ws_size,
                              hipStream_t stream) {
  if (ws_size < (size_t)262144) return;   // mu64[4][64][128] u64
  const float* x_in = (const float*)d_in[0];
  const float* W_sr = (const float*)d_in[1];
  const float* W_ma = (const float*)d_in[2];
  const float* W_ro = (const float*)d_in[3];
  const float* W_ao = (const float*)d_in[4];
  const float* W_ar = (const float*)d_in[5];
  const float* W_ra = (const float*)d_in[6];
  const float* W_a  = (const float*)d_in[7];
  const float* W_y  = (const float*)d_in[8];
  const float* g    = (const float*)d_in[9];
  const float* b    = (const float*)d_in[10];
  float* out = (float*)d_out;
  float* ws  = (float*)d_ws;

  hipLaunchKernelGGL(smn_init, dim3(64), dim3(256), 0, stream, ws);
  hipLaunchKernelGGL(smn_main, dim3(64), dim3(512), 0, stream,
                     x_in, W_sr, W_ma, W_ro, W_ao, W_ar, W_ra, W_a, W_y, g, b,
                     out, ws);
}

// Round 6
// 366.676 us; speedup vs baseline: 2.4602x; 2.4602x over previous
//
#include <hip/hip_runtime.h>

// SimpleMemoryNetwork: T=64,B=128,H=256,NI=2,NO=10, lambda=.95, eta=.5, sample=32, decision=8
// R6: 2D = 64 batch-groups (2 batches) x 4 column-slices (64 cols) = 256 blocks x 512 thr.
// Weight stream per block / step divided by 4 vs R5; all 256 CUs active.
// Barrier-free cross-block dataflow (exact-bit sentinels, P=4 rotating slots):
//   state (a,r) pairs u64, sentinel (-1,-1); c dot-partials f32, sentinel -1.0;
//   mu partials u64 pairs, sentinel NaN(0x7FC00000).
// Re-sentinel discipline: slot n's words are re-sentineled during the CONSUME phase of
// slot n+... (occupant n-1) only after this block's polls of epoch n completed =>
// peers demonstrably finished consuming epoch n-1 (induction via publish order);
// __syncthreads (vmcnt drain) + 3-epoch slack orders re-sentinel before republish.
// o dead for t in (33..55): those steps run only the a/r recurrence (+state exchange).

typedef unsigned long long u64;

#define HH 256
#define NSTEPS 64

// ws layout (float offsets)
#define OFF_ST 0u          // st64[4][128][256] u64
#define OFF_C  262144u     // c_parts[4][33][128][4] f32
#define OFF_MU 329728u     // mu64[4][4][64][32] u64
#define WS_FLOATS 395264u  // ~1.58 MB

#define SENT_STATE   0xBF800000BF800000ull
#define SENT_C       0xBF800000u
#define SENT_MU      0x7FC00000u
#define SENT_MU_PAIR 0x7FC000007FC00000ull

#define AGENT __HIP_MEMORY_SCOPE_AGENT
#define RLX   __ATOMIC_RELAXED

__device__ __forceinline__ u64 ld64(const u64* p){ return __hip_atomic_load(p,RLX,AGENT); }
__device__ __forceinline__ void st64s(u64* p,u64 v){ __hip_atomic_store(p,v,RLX,AGENT); }
__device__ __forceinline__ float ld32f(const float* p){ return __hip_atomic_load(p,RLX,AGENT); }
__device__ __forceinline__ void st32f(float* p,float v){ __hip_atomic_store(p,v,RLX,AGENT); }
__device__ __forceinline__ u64 pack2(float lo,float hi){
  return (u64)__float_as_uint(lo) | ((u64)__float_as_uint(hi)<<32);
}

__global__ __launch_bounds__(256) void smn_init(float* __restrict__ ws,
                                                float* __restrict__ out){
  unsigned i = blockIdx.x*256u + threadIdx.x, st = gridDim.x*256u;
  u64* stp=(u64*)(ws+OFF_ST); float* cp=ws+OFF_C; u64* mp=(u64*)(ws+OFF_MU);
  for (unsigned k=i;k<131072u;k+=st) st64s(&stp[k],SENT_STATE);
  for (unsigned k=i;k<67584u;k+=st)  st32f(&cp[k],-1.0f);
  for (unsigned k=i;k<32768u;k+=st)  st64s(&mp[k],SENT_MU_PAIR);
  for (unsigned k=i;k<10240u;k+=st)  out[k]=0.f;
}

__global__ __launch_bounds__(512) void smn_main(
    const float* __restrict__ x_in, const float* __restrict__ W_sr,
    const float* __restrict__ W_ma, const float* __restrict__ W_ro,
    const float* __restrict__ W_ao, const float* __restrict__ W_ar,
    const float* __restrict__ W_ra, const float* __restrict__ W_a,
    const float* __restrict__ W_y,  const float* __restrict__ gvec,
    const float* __restrict__ bvec, float* __restrict__ out,
    float* __restrict__ ws)
{
  __shared__ __align__(16) float aF[2][HH], rF[2][HH];   // gathered full state(t)
  __shared__ __align__(16) float P[2][32][2][64];        // k-split matvec partials
  __shared__ __align__(16) float r_hist[33][2][64];
  __shared__ __align__(16) float o_hist[33][2][64];
  __shared__ float a_own[2][64], r_own[2][64];
  __shared__ float opre[2][64];
  __shared__ float c_l[33][2];
  __shared__ float mu_l[64];
  __shared__ float muG[16][32][2];
  __shared__ float lam_pow[64];
  __shared__ float x_l[2][5];
  __shared__ float lds_pad[8192];     // LDS > 80KB => 1 block/CU (uniform streaming)

  const int tid = threadIdx.x;
  const int bid = blockIdx.x;
  const int grp = bid >> 2, jsl = bid & 3;
  const int b0 = grp * 2, c0 = jsl * 64;
  const int q = tid & 15, ks = tid >> 4;       // matvec map: col quad, k-slice of 8

  u64*   st64    = (u64*)(ws + OFF_ST);
  float* c_parts = ws + OFF_C;
  u64*   mu64    = (u64*)(ws + OFF_MU);

  if (out == nullptr) lds_pad[tid] = 1.f;      // never true; keeps pad allocated

  // per-thread resident column constants (combine map tid<128 -> b=tid>>6, c=tid&63)
  const int cc = c0 + (tid & 63);
  const float gv  = gvec[cc], bv = bvec[cc];
  const float wma0=W_ma[cc], wma1=W_ma[HH+cc], wma2=W_ma[2*HH+cc];
  const float wsr0=W_sr[cc], wsr1=W_sr[HH+cc];
  if (tid < 64) lam_pow[tid] = powf(0.95f,(float)tid);
  if (tid < 10) x_l[tid/5][tid%5] = x_in[(b0 + tid/5)*5 + tid%5];   // x(0)
  __syncthreads();

  for (int t = 0; t <= NSTEPS; ++t) {
    // ================= A: state(t) own slice =================
    if (t < NSTEPS) {
      if (t == 0) {
        if (tid < 128) {
          int b = tid>>6, c = tid&63;
          float va = fmaxf(x_l[b][2]*wma0 + x_l[b][3]*wma1 + x_l[b][4]*wma2, 0.f);
          float vr = fmaxf(x_l[b][0]*wsr0 + x_l[b][1]*wsr1, 0.f);
          a_own[b][c]=va; r_own[b][c]=vr; r_hist[0][b][c]=vr;
          st64s(&st64[(unsigned)((b0+b)*HH + cc)], pack2(va,vr));
        }
        __syncthreads();
      } else {
        const int kb = ks*8;
        float sa0[8],sa1[8],sr0[8],sr1[8];
        *(float4*)&sa0[0]=*(const float4*)&aF[0][kb]; *(float4*)&sa0[4]=*(const float4*)&aF[0][kb+4];
        *(float4*)&sa1[0]=*(const float4*)&aF[1][kb]; *(float4*)&sa1[4]=*(const float4*)&aF[1][kb+4];
        *(float4*)&sr0[0]=*(const float4*)&rF[0][kb]; *(float4*)&sr0[4]=*(const float4*)&rF[0][kb+4];
        *(float4*)&sr1[0]=*(const float4*)&rF[1][kb]; *(float4*)&sr1[4]=*(const float4*)&rF[1][kb+4];
        float aA[2][4]={{0.f,0.f,0.f,0.f},{0.f,0.f,0.f,0.f}};
        float aR[2][4]={{0.f,0.f,0.f,0.f},{0.f,0.f,0.f,0.f}};
        #pragma unroll
        for (int kk=0; kk<8; ++kk) {
          const int k = kb + kk;
          const float4 wa = *(const float4*)&W_a [k*HH + c0 + q*4];
          const float4 wr = *(const float4*)&W_ra[k*HH + c0 + q*4];
          const float4 wn = *(const float4*)&W_ar[k*HH + c0 + q*4];
          #pragma unroll
          for (int jj=0;jj<4;++jj){
            const float waj=(&wa.x)[jj], wrj=(&wr.x)[jj], wnj=(&wn.x)[jj];
            aA[0][jj] += sa0[kk]*waj + sr0[kk]*wrj;
            aA[1][jj] += sa1[kk]*waj + sr1[kk]*wrj;
            aR[0][jj] += sa0[kk]*wnj;
            aR[1][jj] += sa1[kk]*wnj;
          }
        }
        *(float4*)&P[0][ks][0][q*4] = make_float4(aA[0][0],aA[0][1],aA[0][2],aA[0][3]);
        *(float4*)&P[0][ks][1][q*4] = make_float4(aA[1][0],aA[1][1],aA[1][2],aA[1][3]);
        *(float4*)&P[1][ks][0][q*4] = make_float4(aR[0][0],aR[0][1],aR[0][2],aR[0][3]);
        *(float4*)&P[1][ks][1][q*4] = make_float4(aR[1][0],aR[1][1],aR[1][2],aR[1][3]);
        __syncthreads();
        if (tid < 128) {
          int b=tid>>6, c=tid&63;
          float sa=0.f, sr=0.f;
          #pragma unroll
          for (int e=0;e<32;++e){ sa+=P[0][e][b][c]; sr+=P[1][e][b][c]; }
          float va = fmaxf(sa + x_l[b][2]*wma0 + x_l[b][3]*wma1 + x_l[b][4]*wma2, 0.f);
          float vr = fmaxf(sr + x_l[b][0]*wsr0 + x_l[b][1]*wsr1, 0.f);
          a_own[b][c]=va; r_own[b][c]=vr;
          if (t<=32) r_hist[t][b][c]=vr;
          st64s(&st64[(unsigned)((t&3)*32768) + (unsigned)((b0+b)*HH + cc)], pack2(va,vr));
        }
        __syncthreads();
      }
      if (t+1 < NSTEPS && tid < 10)
        x_l[tid/5][tid%5] = x_in[((t+1)*128 + b0 + tid/5)*5 + tid%5];
    }

    // ================= finish o(t-1): late mu poll =================
    const int tp = t - 1;
    const bool fin = (t >= 1) && (tp <= 32 || tp >= 56);
    if (fin) {
      const int m = (tp <= 32) ? tp : tp - 23;
      {
        const int p = tid & 31, ch = tid >> 5;
        const u64* base = &mu64[(unsigned)(((m&3)*4 + jsl)*64) * 32u];
        float s0=0.f, s1=0.f;
        #pragma unroll
        for (int gg=0; gg<4; ++gg) {
          const u64* ptr = &base[(unsigned)((ch*4+gg)*32 + p)];
          u64 v;
          for (;;){ v = ld64(ptr);
            if ((unsigned)v != SENT_MU && (unsigned)(v>>32) != SENT_MU) break;
            __builtin_amdgcn_s_sleep(1);
          }
          s0 += __uint_as_float((unsigned)v);
          s1 += __uint_as_float((unsigned)(v>>32));
        }
        muG[ch][p][0]=s0; muG[ch][p][1]=s1;
      }
      __syncthreads();
      if (tid < 32) {   // reduce + re-sentinel slot (m+3)%4 (occupant m-1: consumed by all)
        float s0=0.f,s1=0.f;
        #pragma unroll
        for (int ch2=0;ch2<16;++ch2){ s0+=muG[ch2][tid][0]; s1+=muG[ch2][tid][1]; }
        mu_l[2*tid]=s0*(1.f/128.f); mu_l[2*tid+1]=s1*(1.f/128.f);
        st64s(&mu64[(unsigned)((((m+3)&3)*4 + jsl)*64 + grp)*32u + (unsigned)tid], SENT_MU_PAIR);
      }
      __syncthreads();
      if (tid < 128) {
        int b=tid>>6, c=tid&63;
        float o = fmaxf(gv*(opre[b][c]-mu_l[c]) + bv, 0.f);
        opre[b][c]=o;
        if (tp<=32) o_hist[tp][b][c]=o;
      }
      __syncthreads();
      if (tp >= 56 && tid < 320) {
        int ow=tid>>4, l16=tid&15, b=ow/10, n=ow%10;
        float acc=0.f;
        #pragma unroll
        for (int i2=0;i2<4;++i2){ int c=l16*4+i2; acc += opre[b][c]*W_y[(c0+c)*10+n]; }
        acc+=__shfl_xor(acc,1); acc+=__shfl_xor(acc,2);
        acc+=__shfl_xor(acc,4); acc+=__shfl_xor(acc,8);
        if (l16==0) atomicAdd(&out[(tp-56)*1280 + (b0+b)*10 + n], acc);
      }
    }
    if (t == NSTEPS) break;

    const bool live = (t <= 32 || t >= 56);
    const int mc = (t <= 32) ? t : t - 23;
    const int smax = (t-1 < 32) ? (t-1) : 32;

    // ======== dots publish (tid<128) || state gather poll (tid>=128) ========
    if (tid < 128) {
      if (live && smax >= 0) {
        const int l8 = tid & 7;
        for (int pp = tid>>3; pp < (smax+1)*2; pp += 16) {
          const int s = pp>>1, b = pp&1;
          float acc=0.f;
          #pragma unroll
          for (int i2=0;i2<8;++i2){ int c=l8*8+i2; acc += r_own[b][c]*o_hist[s][b][c]; }
          acc+=__shfl_xor(acc,1); acc+=__shfl_xor(acc,2); acc+=__shfl_xor(acc,4);
          if (l8==0) st32f(&c_parts[(unsigned)((((mc&3)*33+s)*128 + b0+b)*4 + jsl)], acc);
        }
      }
      { int b=tid>>6, c=tid&63; aF[b][c0+c]=a_own[b][c]; rF[b][c0+c]=r_own[b][c]; }
    } else {
      const int w = tid - 128;                 // 0..383: 3 peers x 128 words
      const int pi = w >> 7, w2 = w & 127, b = w2>>6, c64 = w2&63;
      const int jp = (jsl + 1 + pi) & 3;
      const u64* ptr = &st64[(unsigned)((t&3)*32768) + (unsigned)((b0+b)*HH + jp*64 + c64)];
      u64 v;
      for (;;){ v = ld64(ptr); if (v != SENT_STATE) break; }
      aF[b][jp*64+c64] = __uint_as_float((unsigned)v);
      rF[b][jp*64+c64] = __uint_as_float((unsigned)(v>>32));
    }
    __syncthreads();
    // state re-sentinel slot (t+3)%4 (occupant t-1; peers' gather(t-1) proven done)
    if (tid < 128) {
      int b=tid>>6;
      st64s(&st64[(unsigned)(((t+3)&3)*32768) + (unsigned)((b0+b)*HH + cc)], SENT_STATE);
    }

    // ================= B: o_pre + apply + mu publish (live only) =================
    if (live) {
      const int kb = ks*8;
      float sa0[8],sa1[8],sr0[8],sr1[8];
      *(float4*)&sa0[0]=*(const float4*)&aF[0][kb]; *(float4*)&sa0[4]=*(const float4*)&aF[0][kb+4];
      *(float4*)&sa1[0]=*(const float4*)&aF[1][kb]; *(float4*)&sa1[4]=*(const float4*)&aF[1][kb+4];
      *(float4*)&sr0[0]=*(const float4*)&rF[0][kb]; *(float4*)&sr0[4]=*(const float4*)&rF[0][kb+4];
      *(float4*)&sr1[0]=*(const float4*)&rF[1][kb]; *(float4*)&sr1[4]=*(const float4*)&rF[1][kb+4];
      float aO[2][4]={{0.f,0.f,0.f,0.f},{0.f,0.f,0.f,0.f}};
      #pragma unroll
      for (int kk=0;kk<8;++kk){
        const int k=kb+kk;
        const float4 wo=*(const float4*)&W_ro[k*HH + c0 + q*4];
        const float4 wq=*(const float4*)&W_ao[k*HH + c0 + q*4];
        #pragma unroll
        for (int jj=0;jj<4;++jj){
          aO[0][jj] += sr0[kk]*(&wo.x)[jj] + sa0[kk]*(&wq.x)[jj];
          aO[1][jj] += sr1[kk]*(&wo.x)[jj] + sa1[kk]*(&wq.x)[jj];
        }
      }
      *(float4*)&P[0][ks][0][q*4] = make_float4(aO[0][0],aO[0][1],aO[0][2],aO[0][3]);
      *(float4*)&P[0][ks][1][q*4] = make_float4(aO[1][0],aO[1][1],aO[1][2],aO[1][3]);
      // c gather (4 j-parts per (s,b), shfl-sum)
      if (smax >= 0 && tid < (smax+1)*8) {
        const int s=tid>>3, b=(tid>>2)&1, jj2=tid&3;
        const float* ptr=&c_parts[(unsigned)((((mc&3)*33+s)*128 + b0+b)*4 + jj2)];
        float v;
        for(;;){ v=ld32f(ptr); if (__float_as_uint(v)!=SENT_C) break; }
        v+=__shfl_xor(v,1); v+=__shfl_xor(v,2);
        if (jj2==0) c_l[s][b]=v;
      }
      __syncthreads();
      // c re-sentinel slot (mc+3)%4 (occupant mc-1: consumed by all group peers)
      if (smax >= 0 && tid >= 128 && tid < 194) {
        const int s=(tid-128)>>1, b=(tid-128)&1;
        st32f(&c_parts[(unsigned)(((((mc+3)&3)*33+s)*128 + b0+b)*4 + jsl)], -1.0f);
      }
      if (tid < 128) {
        int b=tid>>6, c=tid&63;
        float s=0.f;
        #pragma unroll
        for (int e=0;e<32;++e) s+=P[0][e][b][c];
        for (int s2=0;s2<=smax;++s2)
          s += lam_pow[t-1-s2]*0.5f*c_l[s2][b]*r_hist[s2][b][c];
        opre[b][c]=s;
      }
      __syncthreads();
      if (tid < 32) {
        float plo=opre[0][2*tid]+opre[1][2*tid];
        float phi=opre[0][2*tid+1]+opre[1][2*tid+1];
        st64s(&mu64[(unsigned)(((mc&3)*4 + jsl)*64 + grp)*32u + (unsigned)tid], pack2(plo,phi));
      }
    }
  }
}

extern "C" void kernel_launch(void* const* d_in, const int* in_sizes, int n_in,
                              void* d_out, int out_size, void* d_ws, size_t ws_size,
                              hipStream_t stream) {
  if (ws_size < (size_t)WS_FLOATS * 4) return;   // ~1.6 MB scratch
  const float* x_in = (const float*)d_in[0];
  const float* W_sr = (const float*)d_in[1];
  const float* W_ma = (const float*)d_in[2];
  const float* W_ro = (const float*)d_in[3];
  const float* W_ao = (const float*)d_in[4];
  const float* W_ar = (const float*)d_in[5];
  const float* W_ra = (const float*)d_in[6];
  const float* W_a  = (const float*)d_in[7];
  const float* W_y  = (const float*)d_in[8];
  const float* g    = (const float*)d_in[9];
  const float* b    = (const float*)d_in[10];
  float* out = (float*)d_out;
  float* ws  = (float*)d_ws;

  hipLaunchKernelGGL(smn_init, dim3(256), dim3(256), 0, stream, ws, out);
  hipLaunchKernelGGL(smn_main, dim3(256), dim3(512), 0, stream,
                     x_in, W_sr, W_ma, W_ro, W_ao, W_ar, W_ra, W_a, W_y, g, b,
                     out, ws);
}